// Round 2
// 463.227 us; speedup vs baseline: 1.3810x; 1.3810x over previous
//
#include <hip/hip_runtime.h>
#include <math.h>

typedef unsigned short u16;
typedef __bf16 bf16x8 __attribute__((ext_vector_type(8)));
typedef float f32x4 __attribute__((ext_vector_type(4)));
typedef u16 u16x8 __attribute__((ext_vector_type(8)));

#define LTOT 8192
#define KNB  30
#define HDIM 128

__device__ __forceinline__ float bf2f(u16 u){
  unsigned x = ((unsigned)u) << 16;
  return __builtin_bit_cast(float, x);
}
__device__ __forceinline__ u16 f2bf(float f){
  unsigned x = __builtin_bit_cast(unsigned, f);
  x = x + 0x7fffu + ((x >> 16) & 1u);
  return (u16)(x >> 16);
}
// tanh-form GELU: max |err| vs exact ~3e-3, well under threshold slack
__device__ __forceinline__ float gelu_f(float x){
  float u = 0.7978845608028654f * (x + 0.044715f * x * x * x);
  float e = __expf(2.f * u);          // overflow->inf is safe: t->1
  float t = 1.f - 2.f / (e + 1.f);
  return 0.5f * x * (1.f + t);
}
__device__ __forceinline__ void pack8(u16* dst, const float* s){
  float4 a = *(const float4*)s, b = *(const float4*)(s + 4);
  u16x8 p;
  p[0]=f2bf(a.x); p[1]=f2bf(a.y); p[2]=f2bf(a.z); p[3]=f2bf(a.w);
  p[4]=f2bf(b.x); p[5]=f2bf(b.y); p[6]=f2bf(b.z); p[7]=f2bf(b.w);
  *(u16x8*)dst = p;
}

// ---------------------------------------------------------------- transpose
struct TEnt { const float* src; u16* dst; int K; int N; int nb; };
struct TTab { TEnt e[12]; };

__global__ __launch_bounds__(256) void transpose_kernel(TTab t){
  int b = (int)blockIdx.x;
  for (int i = 0; i < 12; ++i){
    int nb = t.e[i].nb;
    if (b < nb){
      int N = t.e[i].N, Kd = t.e[i].K;
      int idx = b * 256 + (int)threadIdx.x;
      if (idx < Kd * N){
        int k = idx / N;
        int n = idx - k * N;
        t.e[i].dst[n * Kd + k] = f2bf(t.e[i].src[(long)k * N + n]);
      }
      return;
    }
    b -= nb;
  }
}

// ------------------------------------------------- per-node precompute GEMMs
// outa = bf16(X @ WTa^T + ba), outc = bf16(X @ WTc^T); weights loaded as
// fragments straight from global (L2-hot), LDS holds only the X tile.
template<bool XF32>
__global__ __launch_bounds__(256) void pre_gemm_kernel(
  const void* __restrict__ X,
  const u16* __restrict__ WTa, const float* __restrict__ ba, u16* __restrict__ outa,
  const u16* __restrict__ WTc, u16* __restrict__ outc)
{
  __shared__ __align__(16) char smem[8704];
  u16* Xs = (u16*)smem;            // [32][136]
  const int tid = threadIdx.x;
  const int wave = tid >> 6, lane = tid & 63, q = lane >> 4, s = lane & 15;
  const int row0 = (int)blockIdx.x * 32;

  for (int i = tid; i < 32 * 16; i += 256){
    int r = i >> 4, cb = i & 15;
    if (XF32) pack8(&Xs[r * 136 + cb * 8], &((const float*)X)[(long)(row0 + r) * HDIM + cb * 8]);
    else *(u16x8*)&Xs[r * 136 + cb * 8] = *(const u16x8*)&((const u16*)X)[(long)(row0 + r) * HDIM + cb * 8];
  }
  __syncthreads();
  for (int w = 0; w < 2; ++w){
    const u16* W = w ? WTc : WTa;
    u16* out = w ? outc : outa;
    f32x4 acc[2][2];
#pragma unroll
    for (int mt = 0; mt < 2; ++mt)
#pragma unroll
      for (int nt = 0; nt < 2; ++nt){ f32x4 z = {0.f,0.f,0.f,0.f}; acc[mt][nt] = z; }
    for (int kt = 0; kt < 4; ++kt){
      bf16x8 b0 = *(const bf16x8*)&W[(wave * 32 + s) * 128 + kt * 32 + q * 8];
      bf16x8 b1 = *(const bf16x8*)&W[(wave * 32 + 16 + s) * 128 + kt * 32 + q * 8];
#pragma unroll
      for (int mt = 0; mt < 2; ++mt){
        bf16x8 af = *(const bf16x8*)&Xs[(mt * 16 + s) * 136 + kt * 32 + q * 8];
        acc[mt][0] = __builtin_amdgcn_mfma_f32_16x16x32_bf16(af, b0, acc[mt][0], 0, 0, 0);
        acc[mt][1] = __builtin_amdgcn_mfma_f32_16x16x32_bf16(af, b1, acc[mt][1], 0, 0, 0);
      }
    }
#pragma unroll
    for (int nt = 0; nt < 2; ++nt){
      int col = wave * 32 + nt * 16 + s;
      float bv = w ? 0.f : ba[col];
#pragma unroll
      for (int mt = 0; mt < 2; ++mt)
#pragma unroll
        for (int r = 0; r < 4; ++r){
          int row = row0 + mt * 16 + q * 4 + r;
          out[(long)row * HDIM + col] = f2bf(acc[mt][nt][r] + bv);
        }
    }
  }
}

// ---------------------------------------------- fused 3-layer message kernel
// 2 nodes = 64 padded edge-rows (32/node, k<30 valid) per workgroup.
// acc[4][2] = 32 AGPRs, leaving ~96 arch VGPRs under the 128-reg cap of
// __launch_bounds__(256,4) -> no scratch spill (the NB=4 version pinned
// VGPR_Count at 64 and spilled ~400B/thread = ~200 MB HBM writes/dispatch).
template<bool EDGE>
__global__ __launch_bounds__(256, 4) void msg_kernel(
  const float* __restrict__ hVin,
  const float* __restrict__ hE,
  const int* __restrict__ Eidx,
  const float* __restrict__ maskA,
  const u16* __restrict__ vsum,   // bf16 [8192][128]: hV@W1a + b1
  const u16* __restrict__ vcg,    // bf16 [8192][128]: hV@W1c (gathered)
  const u16* __restrict__ WTb, const u16* __restrict__ WT2, const u16* __restrict__ WT3,
  const float* __restrict__ b2, const float* __restrict__ b3,
  const float* __restrict__ gam, const float* __restrict__ bet,
  float* __restrict__ out_f32,
  u16* __restrict__ out_b16,
  float* __restrict__ outE)
{
  __shared__ __align__(16) char smem[18944];
  u16*   As   = (u16*)smem;              // [64][136] = 17408 B
  float* ovl  = (float*)smem;            // epilogue overlay (after final MFMA reads)
  float* vbuf = (float*)(smem + 17408);  // [2][128]
  float* mbuf = (float*)(smem + 18432);  // [64]
  int*   nbr  = (int*)(smem + 18688);    // [64]

  const int tid = threadIdx.x;
  const int wave = tid >> 6, lane = tid & 63, q = lane >> 4, s = lane & 15;
  const int node0 = (int)blockIdx.x * 2;

  // stage hE tile (f32 -> bf16), pad rows k=30,31 with zeros
  for (int i = tid; i < 64 * 16; i += 256){
    int r = i >> 4, cb = i & 15, nd = r >> 5, k = r & 31;
    if (k < KNB)
      pack8(&As[r * 136 + cb * 8], &hE[(((long)(node0 + nd) * KNB) + k) * HDIM + cb * 8]);
    else { u16x8 z = {0,0,0,0,0,0,0,0}; *(u16x8*)&As[r * 136 + cb * 8] = z; }
  }
  if (tid < 64){
    int nd = tid >> 5, k = tid & 31;
    int e = (node0 + nd) * KNB + k;
    bool v = (k < KNB);
    nbr[tid] = v ? Eidx[e] : 0;
    if (!EDGE) mbuf[tid] = v ? maskA[e] : 0.f;
  }
  vbuf[tid] = bf2f(vsum[(long)(node0 + (tid >> 7)) * HDIM + (tid & 127)]);

  f32x4 acc[4][2];
  for (int layer = 0; layer < 3; ++layer){
    const u16* W = (layer == 0) ? WTb : ((layer == 1) ? WT2 : WT3);
    __syncthreads();   // staging / previous gelu writes complete
#pragma unroll
    for (int mt = 0; mt < 4; ++mt){ f32x4 z = {0.f,0.f,0.f,0.f}; acc[mt][0] = z; acc[mt][1] = z; }
    for (int kt = 0; kt < 4; ++kt){
      bf16x8 b0 = *(const bf16x8*)&W[(wave * 32 + s) * 128 + kt * 32 + q * 8];
      bf16x8 b1 = *(const bf16x8*)&W[(wave * 32 + 16 + s) * 128 + kt * 32 + q * 8];
#pragma unroll
      for (int mt = 0; mt < 4; ++mt){
        bf16x8 af = *(const bf16x8*)&As[(mt * 16 + s) * 136 + kt * 32 + q * 8];
        acc[mt][0] = __builtin_amdgcn_mfma_f32_16x16x32_bf16(af, b0, acc[mt][0], 0, 0, 0);
        acc[mt][1] = __builtin_amdgcn_mfma_f32_16x16x32_bf16(af, b1, acc[mt][1], 0, 0, 0);
      }
    }
    if (layer < 2){
      __syncthreads();  // all As reads done before overwrite
#pragma unroll
      for (int nt = 0; nt < 2; ++nt){
        int col = wave * 32 + nt * 16 + s;
        float bv = (layer == 1) ? b2[col] : 0.f;
#pragma unroll
        for (int mt = 0; mt < 4; ++mt)
#pragma unroll
          for (int r = 0; r < 4; ++r){
            int row = mt * 16 + q * 4 + r;
            float v = acc[mt][nt][r] + bv;
            if (layer == 0)
              v += vbuf[((row >> 5) << 7) + col] + bf2f(vcg[(long)nbr[row] * HDIM + col]);
            As[row * 136 + col] = f2bf(gelu_f(v));
          }
      }
    }
  }
  __syncthreads();  // final As reads done; As region free for overlay

  if (!EDGE){
    float* dh = ovl;   // [2][128] (overlays As)
#pragma unroll
    for (int nt = 0; nt < 2; ++nt){
      int col = wave * 32 + nt * 16 + s;
      float b3v = b3[col];
#pragma unroll
      for (int ni = 0; ni < 2; ++ni){
        float ss = 0.f;
#pragma unroll
        for (int mh = 0; mh < 2; ++mh){
          int mt = ni * 2 + mh;
#pragma unroll
          for (int r = 0; r < 4; ++r){
            int row = mt * 16 + q * 4 + r;
            ss += (acc[mt][nt][r] + b3v) * mbuf[row];
          }
        }
        ss += __shfl_xor(ss, 16);
        ss += __shfl_xor(ss, 32);
        if (q == 0) dh[ni * 128 + col] = ss * (1.f / 30.f);
      }
    }
    __syncthreads();
    if (wave < 2){
      int node = node0 + wave;    // waves 0,1 handle one node each
      float x0 = hVin[(long)node * HDIM + lane]      + dh[wave * 128 + lane];
      float x1 = hVin[(long)node * HDIM + 64 + lane] + dh[wave * 128 + 64 + lane];
      float sm = x0 + x1, s2 = x0 * x0 + x1 * x1;
#pragma unroll
      for (int o = 32; o; o >>= 1){ sm += __shfl_xor(sm, o); s2 += __shfl_xor(s2, o); }
      float mu = sm * (1.f / 128.f);
      float var = fmaxf(s2 * (1.f / 128.f) - mu * mu, 0.f);
      float rs = rsqrtf(var + 1e-5f);
      float y0 = (x0 - mu) * rs * gam[lane]      + bet[lane];
      float y1 = (x1 - mu) * rs * gam[64 + lane] + bet[64 + lane];
      out_f32[(long)node * HDIM + lane]      = y0;
      out_f32[(long)node * HDIM + 64 + lane] = y1;
      out_b16[(long)node * HDIM + lane]      = f2bf(y0);
      out_b16[(long)node * HDIM + 64 + lane] = f2bf(y1);
    }
  } else {
    float* part  = ovl;          // [64][4]
    float* part2 = ovl + 256;    // [64][4]
    float* muv   = ovl + 512;    // [64]
    float* rsv   = ovl + 576;    // [64]
    // z = m + b3 + hE residual, kept in acc
#pragma unroll
    for (int nt = 0; nt < 2; ++nt){
      int col = wave * 32 + nt * 16 + s;
      float b3v = b3[col];
#pragma unroll
      for (int mt = 0; mt < 4; ++mt)
#pragma unroll
        for (int r = 0; r < 4; ++r){
          int row = mt * 16 + q * 4 + r, nd = row >> 5, k = row & 31;
          float z = acc[mt][nt][r] + b3v;
          if (k < KNB) z += hE[(((long)(node0 + nd) * KNB) + k) * HDIM + col];
          acc[mt][nt][r] = z;
        }
    }
    // per-row partial sums over this wave's 32 cols (reduce over s in-register)
#pragma unroll
    for (int mt = 0; mt < 4; ++mt)
#pragma unroll
      for (int r = 0; r < 4; ++r){
        int row = mt * 16 + q * 4 + r;
        float ps = acc[mt][0][r] + acc[mt][1][r];
        float pq = acc[mt][0][r] * acc[mt][0][r] + acc[mt][1][r] * acc[mt][1][r];
#pragma unroll
        for (int o = 1; o < 16; o <<= 1){ ps += __shfl_xor(ps, o); pq += __shfl_xor(pq, o); }
        if (s == 0){ part[row * 4 + wave] = ps; part2[row * 4 + wave] = pq; }
      }
    __syncthreads();
    if (tid < 64){
      float sm = part[tid*4] + part[tid*4+1] + part[tid*4+2] + part[tid*4+3];
      float sq = part2[tid*4] + part2[tid*4+1] + part2[tid*4+2] + part2[tid*4+3];
      float mu = sm * (1.f / 128.f);
      float var = fmaxf(sq * (1.f / 128.f) - mu * mu, 0.f);
      muv[tid] = mu;
      rsv[tid] = rsqrtf(var + 1e-5f);
    }
    __syncthreads();
#pragma unroll
    for (int nt = 0; nt < 2; ++nt){
      int col = wave * 32 + nt * 16 + s;
      float gv = gam[col], bv = bet[col];
#pragma unroll
      for (int mt = 0; mt < 4; ++mt)
#pragma unroll
        for (int r = 0; r < 4; ++r){
          int row = mt * 16 + q * 4 + r, nd = row >> 5, k = row & 31;
          if (k < KNB){
            float y = (acc[mt][nt][r] - muv[row]) * rsv[row] * gv + bv;
            outE[(((long)(node0 + nd) * KNB) + k) * HDIM + col] = y;
          }
        }
    }
  }
}

// --------------------------------------------------------- fused FFN + LN2
__global__ __launch_bounds__(256) void ffn_kernel(
  const u16* __restrict__ xb, const float* __restrict__ xf,
  const u16* __restrict__ WiT,   // [512][128]
  const u16* __restrict__ WoT,   // [128][512]
  const float* __restrict__ bi, const float* __restrict__ bo,
  const float* __restrict__ g2, const float* __restrict__ be2,
  const float* __restrict__ maskV,
  float* __restrict__ outV, u16* __restrict__ hv2)
{
  __shared__ __align__(16) char smem[18816];
  u16*   Xs = (u16*)smem;              // [32][136]
  u16*   Ts = (u16*)(smem + 8704);     // [32][136]
  float* part  = (float*)(smem + 17408);  // [32][4]
  float* part2 = part + 128;
  float* muv   = part + 256;           // [32]
  float* rsv   = part + 288;           // [32]
  const int tid = threadIdx.x;
  const int wave = tid >> 6, lane = tid & 63, q = lane >> 4, s = lane & 15;
  const int row0 = (int)blockIdx.x * 32;

  for (int i = tid; i < 32 * 16; i += 256){
    int r = i >> 4, cb = i & 15;
    *(u16x8*)&Xs[r * 136 + cb * 8] = *(const u16x8*)&xb[(long)(row0 + r) * HDIM + cb * 8];
  }
  f32x4 yac[2][2];
#pragma unroll
  for (int mt = 0; mt < 2; ++mt)
#pragma unroll
    for (int nt = 0; nt < 2; ++nt){ f32x4 z = {0.f,0.f,0.f,0.f}; yac[mt][nt] = z; }

  for (int j = 0; j < 4; ++j){
    __syncthreads();   // Xs ready (j=0) / previous Ts reads done
    f32x4 tac[2][2];
#pragma unroll
    for (int mt = 0; mt < 2; ++mt)
#pragma unroll
      for (int nt = 0; nt < 2; ++nt){ f32x4 z = {0.f,0.f,0.f,0.f}; tac[mt][nt] = z; }
    for (int kt = 0; kt < 4; ++kt){
      bf16x8 b0 = *(const bf16x8*)&WiT[((long)(j * 128 + wave * 32 + s)) * 128 + kt * 32 + q * 8];
      bf16x8 b1 = *(const bf16x8*)&WiT[((long)(j * 128 + wave * 32 + 16 + s)) * 128 + kt * 32 + q * 8];
#pragma unroll
      for (int mt = 0; mt < 2; ++mt){
        bf16x8 af = *(const bf16x8*)&Xs[(mt * 16 + s) * 136 + kt * 32 + q * 8];
        tac[mt][0] = __builtin_amdgcn_mfma_f32_16x16x32_bf16(af, b0, tac[mt][0], 0, 0, 0);
        tac[mt][1] = __builtin_amdgcn_mfma_f32_16x16x32_bf16(af, b1, tac[mt][1], 0, 0, 0);
      }
    }
#pragma unroll
    for (int nt = 0; nt < 2; ++nt){
      int col = wave * 32 + nt * 16 + s;
      float bv = bi[j * 128 + col];
#pragma unroll
      for (int mt = 0; mt < 2; ++mt)
#pragma unroll
        for (int r = 0; r < 4; ++r){
          int row = mt * 16 + q * 4 + r;
          Ts[row * 136 + col] = f2bf(gelu_f(tac[mt][nt][r] + bv));
        }
    }
    __syncthreads();
    for (int kt = 0; kt < 4; ++kt){
      bf16x8 b0 = *(const bf16x8*)&WoT[((long)(wave * 32 + s)) * 512 + j * 128 + kt * 32 + q * 8];
      bf16x8 b1 = *(const bf16x8*)&WoT[((long)(wave * 32 + 16 + s)) * 512 + j * 128 + kt * 32 + q * 8];
#pragma unroll
      for (int mt = 0; mt < 2; ++mt){
        bf16x8 af = *(const bf16x8*)&Ts[(mt * 16 + s) * 136 + kt * 32 + q * 8];
        yac[mt][0] = __builtin_amdgcn_mfma_f32_16x16x32_bf16(af, b0, yac[mt][0], 0, 0, 0);
        yac[mt][1] = __builtin_amdgcn_mfma_f32_16x16x32_bf16(af, b1, yac[mt][1], 0, 0, 0);
      }
    }
  }
  // z = y + bo + residual (f32), in regs
#pragma unroll
  for (int nt = 0; nt < 2; ++nt){
    int col = wave * 32 + nt * 16 + s;
    float bv = bo[col];
#pragma unroll
    for (int mt = 0; mt < 2; ++mt)
#pragma unroll
      for (int r = 0; r < 4; ++r){
        int row = mt * 16 + q * 4 + r;
        yac[mt][nt][r] += bv + xf[(long)(row0 + row) * HDIM + col];
      }
  }
#pragma unroll
  for (int mt = 0; mt < 2; ++mt)
#pragma unroll
    for (int r = 0; r < 4; ++r){
      int row = mt * 16 + q * 4 + r;
      float ps = yac[mt][0][r] + yac[mt][1][r];
      float pq = yac[mt][0][r] * yac[mt][0][r] + yac[mt][1][r] * yac[mt][1][r];
#pragma unroll
      for (int o = 1; o < 16; o <<= 1){ ps += __shfl_xor(ps, o); pq += __shfl_xor(pq, o); }
      if (s == 0){ part[row * 4 + wave] = ps; part2[row * 4 + wave] = pq; }
    }
  __syncthreads();
  if (tid < 32){
    float sm = part[tid*4] + part[tid*4+1] + part[tid*4+2] + part[tid*4+3];
    float sq = part2[tid*4] + part2[tid*4+1] + part2[tid*4+2] + part2[tid*4+3];
    float mu = sm * (1.f / 128.f);
    float var = fmaxf(sq * (1.f / 128.f) - mu * mu, 0.f);
    muv[tid] = mu;
    rsv[tid] = rsqrtf(var + 1e-5f);
  }
  __syncthreads();
#pragma unroll
  for (int nt = 0; nt < 2; ++nt){
    int col = wave * 32 + nt * 16 + s;
    float gv = g2[col], bv = be2[col];
#pragma unroll
    for (int mt = 0; mt < 2; ++mt)
#pragma unroll
      for (int r = 0; r < 4; ++r){
        int row = mt * 16 + q * 4 + r;
        float y = (yac[mt][nt][r] - muv[row]) * rsv[row] * gv + bv;
        y *= maskV[row0 + row];
        outV[(long)(row0 + row) * HDIM + col] = y;
        hv2[(long)(row0 + row) * HDIM + col] = f2bf(y);
      }
  }
}

// ------------------------------------------------------------------ launch
extern "C" void kernel_launch(void* const* d_in, const int* in_sizes, int n_in,
                              void* d_out, int out_size, void* d_ws, size_t ws_size,
                              hipStream_t stream) {
  const float* hV    = (const float*)d_in[0];
  const float* hE    = (const float*)d_in[1];
  const int*   Eidx  = (const int*)d_in[2];
  const float* maskV = (const float*)d_in[3];
  const float* maskA = (const float*)d_in[4];
  const float* W1  = (const float*)d_in[5];  const float* b1  = (const float*)d_in[6];
  const float* W2  = (const float*)d_in[7];  const float* b2  = (const float*)d_in[8];
  const float* W3  = (const float*)d_in[9];  const float* b3  = (const float*)d_in[10];
  const float* W11 = (const float*)d_in[11]; const float* b11 = (const float*)d_in[12];
  const float* W12 = (const float*)d_in[13]; const float* b12 = (const float*)d_in[14];
  const float* W13 = (const float*)d_in[15]; const float* b13 = (const float*)d_in[16];
  const float* Wi  = (const float*)d_in[17]; const float* bi  = (const float*)d_in[18];
  const float* Wo  = (const float*)d_in[19]; const float* bo  = (const float*)d_in[20];
  const float* g1  = (const float*)d_in[21]; const float* be1 = (const float*)d_in[22];
  const float* g2  = (const float*)d_in[23]; const float* be2 = (const float*)d_in[24];
  const float* g3  = (const float*)d_in[25]; const float* be3 = (const float*)d_in[26];

  char* ws = (char*)d_ws;
  u16* wt = (u16*)ws;
  u16* wtW1a  = wt;
  u16* wtW1b  = wt + 16384;
  u16* wtW1c  = wt + 32768;
  u16* wtW2   = wt + 49152;
  u16* wtW3   = wt + 65536;
  u16* wtW11a = wt + 81920;
  u16* wtW11b = wt + 98304;
  u16* wtW11c = wt + 114688;
  u16* wtW12  = wt + 131072;
  u16* wtW13  = wt + 147456;
  u16* wtWi   = wt + 163840;   // [512][128]
  u16* wtWo   = wt + 229376;   // [128][512]
  size_t off = 589824;
  u16* vsum1   = (u16*)(ws + off); off += 2097152;
  u16* vc      = (u16*)(ws + off); off += 2097152;
  u16* vsum11  = (u16*)(ws + off); off += 2097152;
  u16* vc2     = (u16*)(ws + off); off += 2097152;
  float* hv1_f32 = (float*)(ws + off); off += 4194304;
  u16*   hv1_b16 = (u16*)(ws + off);   off += 2097152;
  u16*   hv2_b16 = (u16*)(ws + off);   off += 2097152;

  float* outV = (float*)d_out;
  float* outE = (float*)d_out + (long)LTOT * HDIM;

  TTab tt;
  tt.e[0]  = { W1,          wtW1a,  128, 128, 64 };
  tt.e[1]  = { W1 + 16384,  wtW1b,  128, 128, 64 };
  tt.e[2]  = { W1 + 32768,  wtW1c,  128, 128, 64 };
  tt.e[3]  = { W2,          wtW2,   128, 128, 64 };
  tt.e[4]  = { W3,          wtW3,   128, 128, 64 };
  tt.e[5]  = { W11,         wtW11a, 128, 128, 64 };
  tt.e[6]  = { W11 + 16384, wtW11b, 128, 128, 64 };
  tt.e[7]  = { W11 + 32768, wtW11c, 128, 128, 64 };
  tt.e[8]  = { W12,         wtW12,  128, 128, 64 };
  tt.e[9]  = { W13,         wtW13,  128, 128, 64 };
  tt.e[10] = { Wi,          wtWi,   128, 512, 256 };
  tt.e[11] = { Wo,          wtWo,   512, 128, 256 };
  transpose_kernel<<<dim3(1152), dim3(256), 0, stream>>>(tt);

  pre_gemm_kernel<true><<<dim3(256), dim3(256), 0, stream>>>(
      hV, wtW1a, b1, vsum1, wtW1c, vc);
  msg_kernel<false><<<dim3(4096), dim3(256), 0, stream>>>(
      hV, hE, Eidx, maskA, vsum1, vc, wtW1b, wtW2, wtW3, b2, b3, g1, be1,
      hv1_f32, hv1_b16, nullptr);
  ffn_kernel<<<dim3(256), dim3(256), 0, stream>>>(
      hv1_b16, hv1_f32, wtWi, wtWo, bi, bo, g2, be2, maskV, outV, hv2_b16);
  pre_gemm_kernel<false><<<dim3(256), dim3(256), 0, stream>>>(
      hv2_b16, wtW11a, b11, vsum11, wtW11c, vc2);
  msg_kernel<true><<<dim3(4096), dim3(256), 0, stream>>>(
      hV, hE, Eidx, maskA, vsum11, vc2, wtW11b, wtW12, wtW13, b12, b13, g3, be3,
      hv1_f32, hv1_b16, outE);
}

// Round 3
// 442.515 us; speedup vs baseline: 1.4457x; 1.0468x over previous
//
#include <hip/hip_runtime.h>
#include <math.h>

typedef unsigned short u16;
typedef __bf16 bf16x8 __attribute__((ext_vector_type(8)));
typedef float f32x4 __attribute__((ext_vector_type(4)));
typedef u16 u16x8 __attribute__((ext_vector_type(8)));

#define LTOT 8192
#define KNB  30
#define HDIM 128

__device__ __forceinline__ float bf2f(u16 u){
  unsigned x = ((unsigned)u) << 16;
  return __builtin_bit_cast(float, x);
}
// f32 -> bf16 RNE via native cast (compiler pairs into v_cvt_pk_bf16_f32)
__device__ __forceinline__ u16 f2bf(float f){
  __bf16 h = (__bf16)f;
  return __builtin_bit_cast(u16, h);
}
__device__ __forceinline__ float fast_exp2(float x){
#if __has_builtin(__builtin_amdgcn_exp2f)
  return __builtin_amdgcn_exp2f(x);
#else
  return exp2f(x);
#endif
}
// tanh-form GELU, rewritten as x*sigmoid-ish with exp2+rcp:
// y = x * (1 - 1/(exp2(x*(C1 + C3*x^2)) + 1));  C1=2*sqrt(2/pi)*log2e,
// C3=0.044715*C1. max |err| vs exact ~3e-3 (same form as before).
__device__ __forceinline__ float gelu_f(float x){
  float x2 = x * x;
  float g  = x * (2.3022082f + 0.10294324f * x2);
  float e  = fast_exp2(g);
  float r  = __builtin_amdgcn_rcpf(e + 1.f);
  return x * (1.f - r);
}
__device__ __forceinline__ void pack8(u16* dst, const float* s){
  float4 a = *(const float4*)s, b = *(const float4*)(s + 4);
  u16x8 p;
  p[0]=f2bf(a.x); p[1]=f2bf(a.y); p[2]=f2bf(a.z); p[3]=f2bf(a.w);
  p[4]=f2bf(b.x); p[5]=f2bf(b.y); p[6]=f2bf(b.z); p[7]=f2bf(b.w);
  *(u16x8*)dst = p;
}

// ---------------------------------------------------------------- transpose
struct TEnt { const float* src; u16* dst; int K; int N; int nb; };
struct TTab { TEnt e[12]; };

__global__ __launch_bounds__(256) void transpose_kernel(TTab t){
  int b = (int)blockIdx.x;
  for (int i = 0; i < 12; ++i){
    int nb = t.e[i].nb;
    if (b < nb){
      int N = t.e[i].N, Kd = t.e[i].K;
      int idx = b * 256 + (int)threadIdx.x;
      if (idx < Kd * N){
        int k = idx / N;
        int n = idx - k * N;
        t.e[i].dst[n * Kd + k] = f2bf(t.e[i].src[(long)k * N + n]);
      }
      return;
    }
    b -= nb;
  }
}

// ------------------------------------------------- per-node precompute GEMMs
template<bool XF32>
__global__ __launch_bounds__(256) void pre_gemm_kernel(
  const void* __restrict__ X,
  const u16* __restrict__ WTa, const float* __restrict__ ba, u16* __restrict__ outa,
  const u16* __restrict__ WTc, u16* __restrict__ outc)
{
  __shared__ __align__(16) char smem[8704];
  u16* Xs = (u16*)smem;            // [32][136]
  const int tid = threadIdx.x;
  const int wave = tid >> 6, lane = tid & 63, q = lane >> 4, s = lane & 15;
  const int row0 = (int)blockIdx.x * 32;

  for (int i = tid; i < 32 * 16; i += 256){
    int r = i >> 4, cb = i & 15;
    if (XF32) pack8(&Xs[r * 136 + cb * 8], &((const float*)X)[(long)(row0 + r) * HDIM + cb * 8]);
    else *(u16x8*)&Xs[r * 136 + cb * 8] = *(const u16x8*)&((const u16*)X)[(long)(row0 + r) * HDIM + cb * 8];
  }
  __syncthreads();
  for (int w = 0; w < 2; ++w){
    const u16* W = w ? WTc : WTa;
    u16* out = w ? outc : outa;
    f32x4 acc[2][2];
#pragma unroll
    for (int mt = 0; mt < 2; ++mt)
#pragma unroll
      for (int nt = 0; nt < 2; ++nt){ f32x4 z = {0.f,0.f,0.f,0.f}; acc[mt][nt] = z; }
    for (int kt = 0; kt < 4; ++kt){
      bf16x8 b0 = *(const bf16x8*)&W[(wave * 32 + s) * 128 + kt * 32 + q * 8];
      bf16x8 b1 = *(const bf16x8*)&W[(wave * 32 + 16 + s) * 128 + kt * 32 + q * 8];
#pragma unroll
      for (int mt = 0; mt < 2; ++mt){
        bf16x8 af = *(const bf16x8*)&Xs[(mt * 16 + s) * 136 + kt * 32 + q * 8];
        acc[mt][0] = __builtin_amdgcn_mfma_f32_16x16x32_bf16(af, b0, acc[mt][0], 0, 0, 0);
        acc[mt][1] = __builtin_amdgcn_mfma_f32_16x16x32_bf16(af, b1, acc[mt][1], 0, 0, 0);
      }
    }
#pragma unroll
    for (int nt = 0; nt < 2; ++nt){
      int col = wave * 32 + nt * 16 + s;
      float bv = w ? 0.f : ba[col];
#pragma unroll
      for (int mt = 0; mt < 2; ++mt)
#pragma unroll
        for (int r = 0; r < 4; ++r){
          int row = row0 + mt * 16 + q * 4 + r;
          out[(long)row * HDIM + col] = f2bf(acc[mt][nt][r] + bv);
        }
    }
  }
}

// ---------------------------------------------- fused 3-layer message kernel
// 2 nodes = 64 padded edge-rows per workgroup. vcg neighbor rows are staged
// into LDS (Vs) with vectorized gathers issued before the layer-0 MFMA,
// replacing 32 scalar global gather loads per thread in the epilogue.
template<bool EDGE>
__global__ __launch_bounds__(256, 4) void msg_kernel(
  const float* __restrict__ hVin,
  const float* __restrict__ hE,
  const int* __restrict__ Eidx,
  const float* __restrict__ maskA,
  const u16* __restrict__ vsum,   // bf16 [8192][128]: hV@W1a + b1
  const u16* __restrict__ vcg,    // bf16 [8192][128]: hV@W1c (gathered)
  const u16* __restrict__ WTb, const u16* __restrict__ WT2, const u16* __restrict__ WT3,
  const float* __restrict__ b2, const float* __restrict__ b3,
  const float* __restrict__ gam, const float* __restrict__ bet,
  float* __restrict__ out_f32,
  u16* __restrict__ out_b16,
  float* __restrict__ outE)
{
  __shared__ __align__(16) char smem[36352];
  u16*   As   = (u16*)smem;              // [64][136] = 17408 B
  float* ovl  = (float*)smem;            // epilogue overlay (after final MFMA reads)
  u16*   Vs   = (u16*)(smem + 17408);    // [64][136] = 17408 B (gathered vcg rows)
  float* vbuf = (float*)(smem + 34816);  // [2][128]
  float* mbuf = (float*)(smem + 35840);  // [64]
  int*   nbr  = (int*)(smem + 36096);    // [64]

  const int tid = threadIdx.x;
  const int wave = tid >> 6, lane = tid & 63, q = lane >> 4, s = lane & 15;
  const int node0 = (int)blockIdx.x * 2;

  // stage hE tile (f32 -> bf16), pad rows k=30,31 with zeros
  for (int i = tid; i < 64 * 16; i += 256){
    int r = i >> 4, cb = i & 15, nd = r >> 5, k = r & 31;
    if (k < KNB)
      pack8(&As[r * 136 + cb * 8], &hE[(((long)(node0 + nd) * KNB) + k) * HDIM + cb * 8]);
    else { u16x8 z = {0,0,0,0,0,0,0,0}; *(u16x8*)&As[r * 136 + cb * 8] = z; }
  }
  if (tid < 64){
    int nd = tid >> 5, k = tid & 31;
    int e = (node0 + nd) * KNB + k;
    bool v = (k < KNB);
    nbr[tid] = v ? Eidx[e] : 0;
    if (!EDGE) mbuf[tid] = v ? maskA[e] : 0.f;
  }
  vbuf[tid] = bf2f(vsum[(long)(node0 + (tid >> 7)) * HDIM + (tid & 127)]);

  __syncthreads();   // As, nbr, vbuf staged

  // gather vcg neighbor rows into Vs (coalesced u16x8 per 16-lane row-chunk);
  // issued before layer-0 MFMA so global latency hides under it
  for (int i = tid; i < 64 * 16; i += 256){
    int r = i >> 4, cb = i & 15;
    *(u16x8*)&Vs[r * 136 + cb * 8] = *(const u16x8*)&vcg[(long)nbr[r] * HDIM + cb * 8];
  }

  f32x4 acc[4][2];
  for (int layer = 0; layer < 3; ++layer){
    const u16* W = (layer == 0) ? WTb : ((layer == 1) ? WT2 : WT3);
    if (layer) __syncthreads();   // previous gelu writes complete
#pragma unroll
    for (int mt = 0; mt < 4; ++mt){ f32x4 z = {0.f,0.f,0.f,0.f}; acc[mt][0] = z; acc[mt][1] = z; }
    for (int kt = 0; kt < 4; ++kt){
      bf16x8 b0 = *(const bf16x8*)&W[(wave * 32 + s) * 128 + kt * 32 + q * 8];
      bf16x8 b1 = *(const bf16x8*)&W[(wave * 32 + 16 + s) * 128 + kt * 32 + q * 8];
#pragma unroll
      for (int mt = 0; mt < 4; ++mt){
        bf16x8 af = *(const bf16x8*)&As[(mt * 16 + s) * 136 + kt * 32 + q * 8];
        acc[mt][0] = __builtin_amdgcn_mfma_f32_16x16x32_bf16(af, b0, acc[mt][0], 0, 0, 0);
        acc[mt][1] = __builtin_amdgcn_mfma_f32_16x16x32_bf16(af, b1, acc[mt][1], 0, 0, 0);
      }
    }
    if (layer < 2){
      __syncthreads();  // all As reads done before overwrite (also orders Vs w->r)
#pragma unroll
      for (int nt = 0; nt < 2; ++nt){
        int col = wave * 32 + nt * 16 + s;
        float bv = (layer == 1) ? b2[col] : 0.f;
        float vb0 = 0.f, vb1 = 0.f;
        if (layer == 0){ vb0 = vbuf[col]; vb1 = vbuf[128 + col]; }
#pragma unroll
        for (int mt = 0; mt < 4; ++mt)
#pragma unroll
          for (int r = 0; r < 4; ++r){
            int row = mt * 16 + q * 4 + r;
            float v = acc[mt][nt][r] + bv;
            if (layer == 0)
              v += (mt < 2 ? vb0 : vb1) + bf2f(Vs[row * 136 + col]);
            As[row * 136 + col] = f2bf(gelu_f(v));
          }
      }
    }
  }
  __syncthreads();  // final As reads done; As region free for overlay

  if (!EDGE){
    float* dh = ovl;   // [2][128] (overlays As)
#pragma unroll
    for (int nt = 0; nt < 2; ++nt){
      int col = wave * 32 + nt * 16 + s;
      float b3v = b3[col];
#pragma unroll
      for (int ni = 0; ni < 2; ++ni){
        float ss = 0.f;
#pragma unroll
        for (int mh = 0; mh < 2; ++mh){
          int mt = ni * 2 + mh;
#pragma unroll
          for (int r = 0; r < 4; ++r){
            int row = mt * 16 + q * 4 + r;
            ss += (acc[mt][nt][r] + b3v) * mbuf[row];
          }
        }
        ss += __shfl_xor(ss, 16);
        ss += __shfl_xor(ss, 32);
        if (q == 0) dh[ni * 128 + col] = ss * (1.f / 30.f);
      }
    }
    __syncthreads();
    if (wave < 2){
      int node = node0 + wave;    // waves 0,1 handle one node each
      float x0 = hVin[(long)node * HDIM + lane]      + dh[wave * 128 + lane];
      float x1 = hVin[(long)node * HDIM + 64 + lane] + dh[wave * 128 + 64 + lane];
      float sm = x0 + x1, s2 = x0 * x0 + x1 * x1;
#pragma unroll
      for (int o = 32; o; o >>= 1){ sm += __shfl_xor(sm, o); s2 += __shfl_xor(s2, o); }
      float mu = sm * (1.f / 128.f);
      float var = fmaxf(s2 * (1.f / 128.f) - mu * mu, 0.f);
      float rs = rsqrtf(var + 1e-5f);
      float y0 = (x0 - mu) * rs * gam[lane]      + bet[lane];
      float y1 = (x1 - mu) * rs * gam[64 + lane] + bet[64 + lane];
      out_f32[(long)node * HDIM + lane]      = y0;
      out_f32[(long)node * HDIM + 64 + lane] = y1;
      out_b16[(long)node * HDIM + lane]      = f2bf(y0);
      out_b16[(long)node * HDIM + 64 + lane] = f2bf(y1);
    }
  } else {
    float* part  = ovl;          // [64][4]
    float* part2 = ovl + 256;    // [64][4]
    float* muv   = ovl + 512;    // [64]
    float* rsv   = ovl + 576;    // [64]
    // z = m + b3 + hE residual, kept in acc
#pragma unroll
    for (int nt = 0; nt < 2; ++nt){
      int col = wave * 32 + nt * 16 + s;
      float b3v = b3[col];
#pragma unroll
      for (int mt = 0; mt < 4; ++mt)
#pragma unroll
        for (int r = 0; r < 4; ++r){
          int row = mt * 16 + q * 4 + r, nd = row >> 5, k = row & 31;
          float z = acc[mt][nt][r] + b3v;
          if (k < KNB) z += hE[(((long)(node0 + nd) * KNB) + k) * HDIM + col];
          acc[mt][nt][r] = z;
        }
    }
    // per-row partial sums over this wave's 32 cols (reduce over s in-register)
#pragma unroll
    for (int mt = 0; mt < 4; ++mt)
#pragma unroll
      for (int r = 0; r < 4; ++r){
        int row = mt * 16 + q * 4 + r;
        float ps = acc[mt][0][r] + acc[mt][1][r];
        float pq = acc[mt][0][r] * acc[mt][0][r] + acc[mt][1][r] * acc[mt][1][r];
#pragma unroll
        for (int o = 1; o < 16; o <<= 1){ ps += __shfl_xor(ps, o); pq += __shfl_xor(pq, o); }
        if (s == 0){ part[row * 4 + wave] = ps; part2[row * 4 + wave] = pq; }
      }
    __syncthreads();
    if (tid < 64){
      float sm = part[tid*4] + part[tid*4+1] + part[tid*4+2] + part[tid*4+3];
      float sq = part2[tid*4] + part2[tid*4+1] + part2[tid*4+2] + part2[tid*4+3];
      float mu = sm * (1.f / 128.f);
      float var = fmaxf(sq * (1.f / 128.f) - mu * mu, 0.f);
      muv[tid] = mu;
      rsv[tid] = rsqrtf(var + 1e-5f);
    }
    __syncthreads();
#pragma unroll
    for (int nt = 0; nt < 2; ++nt){
      int col = wave * 32 + nt * 16 + s;
      float gv = gam[col], bv = bet[col];
#pragma unroll
      for (int mt = 0; mt < 4; ++mt)
#pragma unroll
        for (int r = 0; r < 4; ++r){
          int row = mt * 16 + q * 4 + r, nd = row >> 5, k = row & 31;
          if (k < KNB){
            float y = (acc[mt][nt][r] - muv[row]) * rsv[row] * gv + bv;
            outE[(((long)(node0 + nd) * KNB) + k) * HDIM + col] = y;
          }
        }
    }
  }
}

// --------------------------------------------------------- fused FFN + LN2
__global__ __launch_bounds__(256) void ffn_kernel(
  const u16* __restrict__ xb, const float* __restrict__ xf,
  const u16* __restrict__ WiT,   // [512][128]
  const u16* __restrict__ WoT,   // [128][512]
  const float* __restrict__ bi, const float* __restrict__ bo,
  const float* __restrict__ g2, const float* __restrict__ be2,
  const float* __restrict__ maskV,
  float* __restrict__ outV, u16* __restrict__ hv2)
{
  __shared__ __align__(16) char smem[18816];
  u16*   Xs = (u16*)smem;              // [32][136]
  u16*   Ts = (u16*)(smem + 8704);     // [32][136]
  float* part  = (float*)(smem + 17408);  // [32][4]
  float* part2 = part + 128;
  float* muv   = part + 256;           // [32]
  float* rsv   = part + 288;           // [32]
  const int tid = threadIdx.x;
  const int wave = tid >> 6, lane = tid & 63, q = lane >> 4, s = lane & 15;
  const int row0 = (int)blockIdx.x * 32;

  for (int i = tid; i < 32 * 16; i += 256){
    int r = i >> 4, cb = i & 15;
    *(u16x8*)&Xs[r * 136 + cb * 8] = *(const u16x8*)&xb[(long)(row0 + r) * HDIM + cb * 8];
  }
  f32x4 yac[2][2];
#pragma unroll
  for (int mt = 0; mt < 2; ++mt)
#pragma unroll
    for (int nt = 0; nt < 2; ++nt){ f32x4 z = {0.f,0.f,0.f,0.f}; yac[mt][nt] = z; }

  for (int j = 0; j < 4; ++j){
    __syncthreads();   // Xs ready (j=0) / previous Ts reads done
    f32x4 tac[2][2];
#pragma unroll
    for (int mt = 0; mt < 2; ++mt)
#pragma unroll
      for (int nt = 0; nt < 2; ++nt){ f32x4 z = {0.f,0.f,0.f,0.f}; tac[mt][nt] = z; }
    for (int kt = 0; kt < 4; ++kt){
      bf16x8 b0 = *(const bf16x8*)&WiT[((long)(j * 128 + wave * 32 + s)) * 128 + kt * 32 + q * 8];
      bf16x8 b1 = *(const bf16x8*)&WiT[((long)(j * 128 + wave * 32 + 16 + s)) * 128 + kt * 32 + q * 8];
#pragma unroll
      for (int mt = 0; mt < 2; ++mt){
        bf16x8 af = *(const bf16x8*)&Xs[(mt * 16 + s) * 136 + kt * 32 + q * 8];
        tac[mt][0] = __builtin_amdgcn_mfma_f32_16x16x32_bf16(af, b0, tac[mt][0], 0, 0, 0);
        tac[mt][1] = __builtin_amdgcn_mfma_f32_16x16x32_bf16(af, b1, tac[mt][1], 0, 0, 0);
      }
    }
#pragma unroll
    for (int nt = 0; nt < 2; ++nt){
      int col = wave * 32 + nt * 16 + s;
      float bv = bi[j * 128 + col];
#pragma unroll
      for (int mt = 0; mt < 2; ++mt)
#pragma unroll
        for (int r = 0; r < 4; ++r){
          int row = mt * 16 + q * 4 + r;
          Ts[row * 136 + col] = f2bf(gelu_f(tac[mt][nt][r] + bv));
        }
    }
    __syncthreads();
    for (int kt = 0; kt < 4; ++kt){
      bf16x8 b0 = *(const bf16x8*)&WoT[((long)(wave * 32 + s)) * 512 + j * 128 + kt * 32 + q * 8];
      bf16x8 b1 = *(const bf16x8*)&WoT[((long)(wave * 32 + 16 + s)) * 512 + j * 128 + kt * 32 + q * 8];
#pragma unroll
      for (int mt = 0; mt < 2; ++mt){
        bf16x8 af = *(const bf16x8*)&Ts[(mt * 16 + s) * 136 + kt * 32 + q * 8];
        yac[mt][0] = __builtin_amdgcn_mfma_f32_16x16x32_bf16(af, b0, yac[mt][0], 0, 0, 0);
        yac[mt][1] = __builtin_amdgcn_mfma_f32_16x16x32_bf16(af, b1, yac[mt][1], 0, 0, 0);
      }
    }
  }
  // z = y + bo + residual (f32), in regs
#pragma unroll
  for (int nt = 0; nt < 2; ++nt){
    int col = wave * 32 + nt * 16 + s;
    float bv = bo[col];
#pragma unroll
    for (int mt = 0; mt < 2; ++mt)
#pragma unroll
      for (int r = 0; r < 4; ++r){
        int row = mt * 16 + q * 4 + r;
        yac[mt][nt][r] += bv + xf[(long)(row0 + row) * HDIM + col];
      }
  }
#pragma unroll
  for (int mt = 0; mt < 2; ++mt)
#pragma unroll
    for (int r = 0; r < 4; ++r){
      int row = mt * 16 + q * 4 + r;
      float ps = yac[mt][0][r] + yac[mt][1][r];
      float pq = yac[mt][0][r] * yac[mt][0][r] + yac[mt][1][r] * yac[mt][1][r];
#pragma unroll
      for (int o = 1; o < 16; o <<= 1){ ps += __shfl_xor(ps, o); pq += __shfl_xor(pq, o); }
      if (s == 0){ part[row * 4 + wave] = ps; part2[row * 4 + wave] = pq; }
    }
  __syncthreads();
  if (tid < 32){
    float sm = part[tid*4] + part[tid*4+1] + part[tid*4+2] + part[tid*4+3];
    float sq = part2[tid*4] + part2[tid*4+1] + part2[tid*4+2] + part2[tid*4+3];
    float mu = sm * (1.f / 128.f);
    float var = fmaxf(sq * (1.f / 128.f) - mu * mu, 0.f);
    muv[tid] = mu;
    rsv[tid] = rsqrtf(var + 1e-5f);
  }
  __syncthreads();
#pragma unroll
  for (int nt = 0; nt < 2; ++nt){
    int col = wave * 32 + nt * 16 + s;
    float gv = g2[col], bv = be2[col];
#pragma unroll
    for (int mt = 0; mt < 2; ++mt)
#pragma unroll
      for (int r = 0; r < 4; ++r){
        int row = mt * 16 + q * 4 + r;
        float y = (yac[mt][nt][r] - muv[row]) * rsv[row] * gv + bv;
        y *= maskV[row0 + row];
        outV[(long)(row0 + row) * HDIM + col] = y;
        hv2[(long)(row0 + row) * HDIM + col] = f2bf(y);
      }
  }
}

// ------------------------------------------------------------------ launch
extern "C" void kernel_launch(void* const* d_in, const int* in_sizes, int n_in,
                              void* d_out, int out_size, void* d_ws, size_t ws_size,
                              hipStream_t stream) {
  const float* hV    = (const float*)d_in[0];
  const float* hE    = (const float*)d_in[1];
  const int*   Eidx  = (const int*)d_in[2];
  const float* maskV = (const float*)d_in[3];
  const float* maskA = (const float*)d_in[4];
  const float* W1  = (const float*)d_in[5];  const float* b1  = (const float*)d_in[6];
  const float* W2  = (const float*)d_in[7];  const float* b2  = (const float*)d_in[8];
  const float* W3  = (const float*)d_in[9];  const float* b3  = (const float*)d_in[10];
  const float* W11 = (const float*)d_in[11]; const float* b11 = (const float*)d_in[12];
  const float* W12 = (const float*)d_in[13]; const float* b12 = (const float*)d_in[14];
  const float* W13 = (const float*)d_in[15]; const float* b13 = (const float*)d_in[16];
  const float* Wi  = (const float*)d_in[17]; const float* bi  = (const float*)d_in[18];
  const float* Wo  = (const float*)d_in[19]; const float* bo  = (const float*)d_in[20];
  const float* g1  = (const float*)d_in[21]; const float* be1 = (const float*)d_in[22];
  const float* g2  = (const float*)d_in[23]; const float* be2 = (const float*)d_in[24];
  const float* g3  = (const float*)d_in[25]; const float* be3 = (const float*)d_in[26];

  char* ws = (char*)d_ws;
  u16* wt = (u16*)ws;
  u16* wtW1a  = wt;
  u16* wtW1b  = wt + 16384;
  u16* wtW1c  = wt + 32768;
  u16* wtW2   = wt + 49152;
  u16* wtW3   = wt + 65536;
  u16* wtW11a = wt + 81920;
  u16* wtW11b = wt + 98304;
  u16* wtW11c = wt + 114688;
  u16* wtW12  = wt + 131072;
  u16* wtW13  = wt + 147456;
  u16* wtWi   = wt + 163840;   // [512][128]
  u16* wtWo   = wt + 229376;   // [128][512]
  size_t off = 589824;
  u16* vsum1   = (u16*)(ws + off); off += 2097152;
  u16* vc      = (u16*)(ws + off); off += 2097152;
  u16* vsum11  = (u16*)(ws + off); off += 2097152;
  u16* vc2     = (u16*)(ws + off); off += 2097152;
  float* hv1_f32 = (float*)(ws + off); off += 4194304;
  u16*   hv1_b16 = (u16*)(ws + off);   off += 2097152;
  u16*   hv2_b16 = (u16*)(ws + off);   off += 2097152;

  float* outV = (float*)d_out;
  float* outE = (float*)d_out + (long)LTOT * HDIM;

  TTab tt;
  tt.e[0]  = { W1,          wtW1a,  128, 128, 64 };
  tt.e[1]  = { W1 + 16384,  wtW1b,  128, 128, 64 };
  tt.e[2]  = { W1 + 32768,  wtW1c,  128, 128, 64 };
  tt.e[3]  = { W2,          wtW2,   128, 128, 64 };
  tt.e[4]  = { W3,          wtW3,   128, 128, 64 };
  tt.e[5]  = { W11,         wtW11a, 128, 128, 64 };
  tt.e[6]  = { W11 + 16384, wtW11b, 128, 128, 64 };
  tt.e[7]  = { W11 + 32768, wtW11c, 128, 128, 64 };
  tt.e[8]  = { W12,         wtW12,  128, 128, 64 };
  tt.e[9]  = { W13,         wtW13,  128, 128, 64 };
  tt.e[10] = { Wi,          wtWi,   128, 512, 256 };
  tt.e[11] = { Wo,          wtWo,   512, 128, 256 };
  transpose_kernel<<<dim3(1152), dim3(256), 0, stream>>>(tt);

  pre_gemm_kernel<true><<<dim3(256), dim3(256), 0, stream>>>(
      hV, wtW1a, b1, vsum1, wtW1c, vc);
  msg_kernel<false><<<dim3(4096), dim3(256), 0, stream>>>(
      hV, hE, Eidx, maskA, vsum1, vc, wtW1b, wtW2, wtW3, b2, b3, g1, be1,
      hv1_f32, hv1_b16, nullptr);
  ffn_kernel<<<dim3(256), dim3(256), 0, stream>>>(
      hv1_b16, hv1_f32, wtWi, wtWo, bi, bo, g2, be2, maskV, outV, hv2_b16);
  pre_gemm_kernel<false><<<dim3(256), dim3(256), 0, stream>>>(
      hv2_b16, wtW11a, b11, vsum11, wtW11c, vc2);
  msg_kernel<true><<<dim3(4096), dim3(256), 0, stream>>>(
      hV, hE, Eidx, maskA, vsum11, vc2, wtW11b, wtW12, wtW13, b12, b13, g3, be3,
      hv1_f32, hv1_b16, outE);
}